// Round 1
// baseline (1787.934 us; speedup 1.0000x reference)
//
#include <hip/hip_runtime.h>
#include <math.h>

#define P    13
#define PP   169            // 13*13
#define NIMG 4
#define HIMG 256
#define HP   280            // 256 + 2*12
#define HO   268            // 280 - 13 + 1
#define TM   4              // tile rows (ho)
#define TN   16             // tile cols (wo)
#define TCOLS 64            // TM*TN
#define THREADS 256

// ws layout (float offsets)
#define OFF_PMT   0
#define OFF_PINVT (OFF_PMT + PP*PP)          // 28561
#define OFF_XPAD  (OFF_PINVT + PP*PP)        // 57122
#define OFF_WMAP  (OFF_XPAD + NIMG*HP*HP)    // 370722
#define OFF_NUM   (OFF_WMAP + NIMG*HO*HO)    // 658018
// total = 971618 floats ~ 3.9 MB

__global__ void pad_kernel(const float* __restrict__ x, float* __restrict__ xpad) {
    int idx = blockIdx.x * blockDim.x + threadIdx.x;
    if (idx >= NIMG*HP*HP) return;
    int j = idx % HP; int t = idx / HP; int i = t % HP; int n = t / HP;
    int mi = i - (P-1); mi = (mi < 0) ? -mi : mi; mi = (mi >= HIMG) ? (2*(HIMG-1) - mi) : mi;
    int mj = j - (P-1); mj = (mj < 0) ? -mj : mj; mj = (mj >= HIMG) ? (2*(HIMG-1) - mj) : mj;
    xpad[idx] = 2.0f * x[(n*HIMG + mi)*HIMG + mj] - 1.0f;
}

// Single-block Gauss-Jordan inversion with partial (row) pivoting; matrix in LDS.
// Also writes PmT (transpose of Pm1) for coalesced A-column access in GEMM1.
__global__ __launch_bounds__(1024) void invert_kernel(const float* __restrict__ Pm1,
                                                      float* __restrict__ PmT,
                                                      float* __restrict__ PinvT) {
    extern __shared__ float sm[];
    float* A    = sm;                    // PP*PP
    float* dcol = sm + PP*PP;            // PP
    int*   perm = (int*)(dcol + PP);     // PP
    int*   s_piv = perm + PP;            // 1
    int tid = threadIdx.x;

    for (int idx = tid; idx < PP*PP; idx += 1024) A[idx] = Pm1[idx];
    __syncthreads();
    for (int idx = tid; idx < PP*PP; idx += 1024) {
        int jj = idx / PP, ii = idx - jj*PP;
        PmT[idx] = A[ii*PP + jj];        // PmT[j][i] = Pm1[i][j]
    }
    __syncthreads();

    for (int k = 0; k < PP; ++k) {
        // pivot search over column k (rows >= k), wave 0 only
        if (tid < 64) {
            float best = -1.0f; int bidx = k;
            for (int i = k + tid; i < PP; i += 64) {
                float v = fabsf(A[i*PP + k]);
                if (v > best) { best = v; bidx = i; }
            }
            for (int off = 32; off > 0; off >>= 1) {
                float ov = __shfl_down(best, off);
                int   oi = __shfl_down(bidx, off);
                if (ov > best) { best = ov; bidx = oi; }
            }
            if (tid == 0) { s_piv[0] = bidx; perm[k] = bidx; }
        }
        __syncthreads();
        int p = s_piv[0];
        if (p != k && tid < PP) {
            float tmp = A[k*PP + tid]; A[k*PP + tid] = A[p*PP + tid]; A[p*PP + tid] = tmp;
        }
        __syncthreads();
        float pv = A[k*PP + k];
        __syncthreads();                 // everyone reads pv before row-k writes
        float pinvv = 1.0f / pv;
        if (tid < PP) {
            float v = A[k*PP + tid];
            A[k*PP + tid] = (tid == k) ? pinvv : v * pinvv;
        }
        __syncthreads();
        if (tid < PP) dcol[tid] = A[tid*PP + k];   // stash column k pre-elimination
        __syncthreads();
        int jt = tid & 127;
        int it = tid >> 7;
        float pr0 = A[k*PP + jt];
        bool has2 = (jt + 128) < PP;
        float pr1 = has2 ? A[k*PP + jt + 128] : 0.0f;
        for (int i = it; i < PP; i += 8) {
            if (i == k) continue;
            float dum = dcol[i];
            float v0 = (jt == k) ? 0.0f : A[i*PP + jt];
            A[i*PP + jt] = v0 - pr0 * dum;
            if (has2) {
                int j1 = jt + 128;
                float v1 = (j1 == k) ? 0.0f : A[i*PP + j1];
                A[i*PP + j1] = v1 - pr1 * dum;
            }
        }
        __syncthreads();
    }
    // undo row pivots as column swaps, reverse order
    for (int k = PP - 1; k >= 0; --k) {
        int p = perm[k];
        if (p != k && tid < PP) {
            float tmp = A[tid*PP + k]; A[tid*PP + k] = A[tid*PP + p]; A[tid*PP + p] = tmp;
        }
        __syncthreads();
    }
    for (int idx = tid; idx < PP*PP; idx += 1024) {
        int jj = idx / PP, ii = idx - jj*PP;
        PinvT[idx] = A[ii*PP + jj];      // PinvT[j][i] = Pinv[i][j]
    }
}

// Fused: patches -> t = Pm1@patches -> threshold -> count/w -> rec = Pinv@t
//        -> rec*w -> fold (overlap-add) into num via footprint atomics.
// Block = 64 patch positions (4 ho x 16 wo), 256 threads.
// Thread = 16 col-group x 16 row-thread; owns 4 cols, 12 rows (3 quads of 4).
__global__ __launch_bounds__(THREADS) void fused_kernel(
    const float* __restrict__ xpad,
    const float* __restrict__ PmT,
    const float* __restrict__ PinvT,
    const float* __restrict__ sigma_,
    float* __restrict__ wmap,
    float* __restrict__ num)
{
    __shared__ __align__(16) float xr[16][28];        // x region for this tile
    __shared__ __align__(16) float Abuf[13][192];     // K-chunk of A (padded rows->192)
    __shared__ __align__(16) float tbuf[PP][TCOLS];   // thresholded t tile
    __shared__ float wbuf[TCOLS];
    __shared__ int   cnt[TCOLS];
    __shared__ __align__(16) float fp[16*28];         // fold footprint

    int tid = threadIdx.x;
    int cg  = tid & 15;          // column group: cols c = cg*4 + q
    int rt  = tid >> 4;          // row thread
    int tr  = cg >> 2;           // tile row of my columns (c>>4)
    int tcb = (cg & 3) * 4;      // tile col base (c&15)
    int n   = blockIdx.z;
    int ho0 = blockIdx.y * TM;
    int wo0 = blockIdx.x * TN;
    float lam = 6.0f * sigma_[0];   // 3 * (2*sigma_)

    const float* xp = xpad + n*HP*HP;
    for (int idx = tid; idx < 16*28; idx += THREADS) {
        int i = idx / 28, j = idx - (idx/28)*28;
        int gj = wo0 + j; gj = (gj > HP-1) ? (HP-1) : gj;   // clamp (invalid cols get w=0)
        xr[i][j] = xp[(ho0 + i)*HP + gj];
    }
    if (tid < TCOLS) cnt[tid] = 0;
    __syncthreads();

    float acc[3][4][4];
    #pragma unroll
    for (int g = 0; g < 3; ++g)
      #pragma unroll
      for (int e = 0; e < 4; ++e)
        #pragma unroll
        for (int q = 0; q < 4; ++q) acc[g][e][q] = 0.0f;

    // ---- GEMM1: t = Pm1 @ patches ; patches[k=(di,dj)][c=(tr,tc)] = xr[tr+di][tc+dj]
    for (int kc = 0; kc < 13; ++kc) {            // kc == di
        for (int idx = tid; idx < 13*192; idx += THREADS) {
            int row = idx / 192, col = idx - row*192;
            Abuf[row][col] = (col < PP) ? PmT[(kc*13 + row)*PP + col] : 0.0f;
        }
        __syncthreads();
        #pragma unroll
        for (int kk = 0; kk < 13; ++kk) {        // kk == dj
            float bv[4];
            #pragma unroll
            for (int q = 0; q < 4; ++q) bv[q] = xr[tr + kc][tcb + kk + q];
            #pragma unroll
            for (int g = 0; g < 3; ++g) {
                const float4 a = *reinterpret_cast<const float4*>(&Abuf[kk][4*(rt + 16*g)]);
                float av[4] = {a.x, a.y, a.z, a.w};
                #pragma unroll
                for (int e = 0; e < 4; ++e)
                  #pragma unroll
                  for (int q = 0; q < 4; ++q)
                    acc[g][e][q] += av[e] * bv[q];
            }
        }
        __syncthreads();
    }

    // ---- threshold, store t, count nonzeros (rows 1..168)
    int cadd[4] = {0,0,0,0};
    #pragma unroll
    for (int g = 0; g < 3; ++g) {
      #pragma unroll
      for (int e = 0; e < 4; ++e) {
        int r = 4*(rt + 16*g) + e;
        if (r < PP) {
            float tvv[4];
            #pragma unroll
            for (int q = 0; q < 4; ++q) {
                float qv = acc[g][e][q] / lam;
                bool keep = fabsf(qv) > 1.0f;
                tvv[q] = keep ? qv * lam : 0.0f;
                if (r > 0) cadd[q] += keep ? 1 : 0;
            }
            float4 tv; tv.x = tvv[0]; tv.y = tvv[1]; tv.z = tvv[2]; tv.w = tvv[3];
            *reinterpret_cast<float4*>(&tbuf[r][cg*4]) = tv;
        }
      }
    }
    #pragma unroll
    for (int q = 0; q < 4; ++q) if (cadd[q]) atomicAdd(&cnt[cg*4 + q], cadd[q]);
    __syncthreads();
    if (tid < TCOLS) {
        int c = tid; int tr2 = c >> 4, tc2 = c & 15;
        int wo = wo0 + tc2;
        float w = 1.0f / (1.0f + (float)cnt[c]);
        if (wo >= HO) w = 0.0f;
        wbuf[c] = w;
        if (wo < HO) wmap[(n*HO + ho0 + tr2)*HO + wo] = w;
    }

    // ---- GEMM2: rec = Pinv @ t
    #pragma unroll
    for (int g = 0; g < 3; ++g)
      #pragma unroll
      for (int e = 0; e < 4; ++e)
        #pragma unroll
        for (int q = 0; q < 4; ++q) acc[g][e][q] = 0.0f;

    for (int kc = 0; kc < 13; ++kc) {
        __syncthreads();   // protect Abuf from previous chunk's readers
        for (int idx = tid; idx < 13*192; idx += THREADS) {
            int row = idx / 192, col = idx - row*192;
            Abuf[row][col] = (col < PP) ? PinvT[(kc*13 + row)*PP + col] : 0.0f;
        }
        __syncthreads();
        #pragma unroll
        for (int kk = 0; kk < 13; ++kk) {
            const float4 b = *reinterpret_cast<const float4*>(&tbuf[kc*13 + kk][cg*4]);
            float bv[4] = {b.x, b.y, b.z, b.w};
            #pragma unroll
            for (int g = 0; g < 3; ++g) {
                const float4 a = *reinterpret_cast<const float4*>(&Abuf[kk][4*(rt + 16*g)]);
                float av[4] = {a.x, a.y, a.z, a.w};
                #pragma unroll
                for (int e = 0; e < 4; ++e)
                  #pragma unroll
                  for (int q = 0; q < 4; ++q)
                    acc[g][e][q] += av[e] * bv[q];
            }
        }
    }
    __syncthreads();

    // ---- scale by w, fold into footprint, commit to num
    for (int idx = tid; idx < 16*28; idx += THREADS) fp[idx] = 0.0f;
    float wv[4];
    #pragma unroll
    for (int q = 0; q < 4; ++q) wv[q] = wbuf[cg*4 + q];
    __syncthreads();
    #pragma unroll
    for (int g = 0; g < 3; ++g) {
      #pragma unroll
      for (int e = 0; e < 4; ++e) {
        int r = 4*(rt + 16*g) + e;
        if (r < PP) {
            int di = r / 13, dj = r - di*13;
            float* base = &fp[(tr + di)*28 + tcb + dj];
            #pragma unroll
            for (int q = 0; q < 4; ++q) atomicAdd(base + q, acc[g][e][q] * wv[q]);
        }
      }
    }
    __syncthreads();
    float* nump = num + n*HP*HP;
    for (int idx = tid; idx < 16*28; idx += THREADS) {
        int i = idx / 28, j = idx - (idx/28)*28;
        int gj = wo0 + j;
        if (gj < HP) atomicAdd(&nump[(ho0 + i)*HP + gj], fp[idx]);
    }
}

// out(y,x) = (num(y+12,x+12) / sum_{13x13 box} w + 1) / 2
__global__ __launch_bounds__(256) void final_kernel(const float* __restrict__ num,
                                                    const float* __restrict__ wmap,
                                                    float* __restrict__ out)
{
    __shared__ float wr[28][28];
    int tid = threadIdx.x;
    int n = blockIdx.z;
    int y0 = blockIdx.y * 16, x0 = blockIdx.x * 16;
    const float* wp = wmap + n*HO*HO;
    for (int idx = tid; idx < 28*28; idx += 256) {
        int i = idx / 28, j = idx - (idx/28)*28;
        wr[i][j] = wp[(y0 + i)*HO + (x0 + j)];
    }
    __syncthreads();
    int py = tid >> 4, px = tid & 15;
    float dv = 0.0f;
    #pragma unroll
    for (int a = 0; a < 13; ++a)
      #pragma unroll
      for (int b = 0; b < 13; ++b)
        dv += wr[py + a][px + b];
    int y = y0 + py, x = x0 + px;
    float nv = num[(n*HP + (y + 12))*HP + (x + 12)];
    out[(n*HIMG + y)*HIMG + x] = (nv / dv + 1.0f) * 0.5f;
}

extern "C" void kernel_launch(void* const* d_in, const int* in_sizes, int n_in,
                              void* d_out, int out_size, void* d_ws, size_t ws_size,
                              hipStream_t stream) {
    const float* x      = (const float*)d_in[0];
    const float* sigma_ = (const float*)d_in[1];
    const float* Pm1    = (const float*)d_in[2];
    float* ws    = (float*)d_ws;
    float* PmT   = ws + OFF_PMT;
    float* PinvT = ws + OFF_PINVT;
    float* xpad  = ws + OFF_XPAD;
    float* wmap  = ws + OFF_WMAP;
    float* num   = ws + OFF_NUM;
    float* out   = (float*)d_out;

    hipMemsetAsync(num, 0, (size_t)NIMG*HP*HP*sizeof(float), stream);
    pad_kernel<<<(NIMG*HP*HP + 255)/256, 256, 0, stream>>>(x, xpad);
    size_t inv_lds = (size_t)(PP*PP + PP)*sizeof(float) + (size_t)(PP + 1)*sizeof(int);
    invert_kernel<<<1, 1024, inv_lds, stream>>>(Pm1, PmT, PinvT);
    dim3 grid((HO + TN - 1)/TN, HO/TM, NIMG);   // 17 x 67 x 4
    fused_kernel<<<grid, THREADS, 0, stream>>>(xpad, PmT, PinvT, sigma_, wmap, num);
    dim3 gridD(HIMG/16, HIMG/16, NIMG);         // 16 x 16 x 4
    final_kernel<<<gridD, 256, 0, stream>>>(num, wmap, out);
}

// Round 2
// 1069.277 us; speedup vs baseline: 1.6721x; 1.6721x over previous
//
#include <hip/hip_runtime.h>
#include <math.h>

#define P    13
#define PP   169
#define NIMG 4
#define HIMG 256
#define HP   280            // 256 + 2*12
#define HO   268            // 280 - 13 + 1

typedef __attribute__((ext_vector_type(8))) short short8_t;
typedef __attribute__((ext_vector_type(4))) float f32x4;

__device__ __forceinline__ ushort f2bf(float x) {
    union { float f; unsigned u; } a; a.f = x;
    unsigned r = a.u + 0x7fffu + ((a.u >> 16) & 1u);   // RNE
    return (ushort)(r >> 16);
}
__device__ __forceinline__ float bf2f(ushort b) {
    union { float f; unsigned u; } a; a.u = ((unsigned)b) << 16;
    return a.f;
}

// ---------------- pad (verified round 1) ----------------
__global__ void pad_kernel(const float* __restrict__ x, float* __restrict__ xpad) {
    int idx = blockIdx.x * blockDim.x + threadIdx.x;
    if (idx >= NIMG*HP*HP) return;
    int j = idx % HP; int t = idx / HP; int i = t % HP; int n = t / HP;
    int mi = i - (P-1); mi = (mi < 0) ? -mi : mi; mi = (mi >= HIMG) ? (2*(HIMG-1) - mi) : mi;
    int mj = j - (P-1); mj = (mj < 0) ? -mj : mj; mj = (mj >= HIMG) ? (2*(HIMG-1) - mj) : mj;
    xpad[idx] = 2.0f * x[(n*HIMG + mi)*HIMG + mj] - 1.0f;
}

// ---------------- prep1: Pm1 -> MFMA frag layout, split bf16 hi/lo ----------------
// layout (ushort): [ks 0..6][plane hi/lo][mt 0..10][lane 0..63][j 0..7]
// value = Pm1[row][di*13+dj], row = mt*16+(lane&15), kpad = ks*32+8*(lane>>4)+j,
// di = kpad>>4, dj = kpad&15 ; zero outside (row<169, di<13, dj<13)
__global__ __launch_bounds__(256) void prep1_kernel(const float* __restrict__ Pm1,
                                                    ushort* __restrict__ prep1) {
    int idx = blockIdx.x*256 + threadIdx.x;
    if (idx >= 7*11*512) return;
    int j    = idx & 7;
    int lane = (idx >> 3) & 63;
    int rest = idx >> 9;
    int mt   = rest % 11;
    int ks   = rest / 11;
    int row  = mt*16 + (lane & 15);
    int kpad = ks*32 + 8*(lane>>4) + j;
    int di = kpad >> 4, dj = kpad & 15;
    float val = (row < PP && di < 13 && dj < 13) ? Pm1[row*PP + di*13 + dj] : 0.0f;
    ushort h = f2bf(val);
    ushort lo = f2bf(val - bf2f(h));
    prep1[((ks*2+0)*11 + mt)*512 + lane*8 + j] = h;
    prep1[((ks*2+1)*11 + mt)*512 + lane*8 + j] = lo;
}

// ---------------- invert: Gauss-Jordan w/ partial pivoting, 2 barriers/iter ----------------
// Matrix in LDS [169][172 pad]. Row swap folded into src-row remap; pivot search
// done redundantly per wave (deterministic butterfly). Tail writes prep2 frag layout.
#define AS 172
__global__ __launch_bounds__(512, 2) void invert_kernel(const float* __restrict__ Pm1,
                                                        ushort* __restrict__ prep2) {
    extern __shared__ float sm[];
    float* A   = sm;                       // 169*172 floats
    int* perm  = (int*)(sm + PP*AS);       // 169 ints
    float4* A4 = reinterpret_cast<float4*>(A);   // row stride 43 float4
    int tid = threadIdx.x;
    int l64 = tid & 63;

    // load A (pad cols 169..171 = 0)
    for (int idx = tid; idx < PP*43; idx += 512) {
        int row = (int)(((unsigned)idx * 48771u) >> 21);   // idx/43 exact for idx<7267
        int qj = idx - row*43;
        float4 v;
        v.x = (qj*4+0 < PP) ? Pm1[row*PP + qj*4+0] : 0.0f;
        v.y = (qj*4+1 < PP) ? Pm1[row*PP + qj*4+1] : 0.0f;
        v.z = (qj*4+2 < PP) ? Pm1[row*PP + qj*4+2] : 0.0f;
        v.w = (qj*4+3 < PP) ? Pm1[row*PP + qj*4+3] : 0.0f;
        A4[row*43 + qj] = v;
    }
    __syncthreads();

    // static slot ownership: idx = tid + 512*s over 7267 quads
    int rows_[15], qjs_[15];
#pragma unroll
    for (int s = 0; s < 15; ++s) {
        int idx = tid + (s << 9);
        int row = (int)(((unsigned)idx * 48771u) >> 21);
        rows_[s] = row;
        qjs_[s] = idx - row*43;
    }

    float4 Qq[15], Pq[15];
    float dums[15];

    for (int k = 0; k < PP; ++k) {
        // --- phase A: pivot find (redundant per wave) + reads ---
        float best = -1.0f; int bidx = k;
        for (int i = k + l64; i < PP; i += 64) {
            float v = fabsf(A[i*AS + k]);
            if (v > best) { best = v; bidx = i; }
        }
#pragma unroll
        for (int m = 1; m < 64; m <<= 1) {
            float ov = __shfl_xor(best, m);
            int   oi = __shfl_xor(bidx, m);
            if (ov > best || (ov == best && oi < bidx)) { best = ov; bidx = oi; }
        }
        int p = bidx;
        float pv = A[p*AS + k];
#pragma unroll
        for (int s = 0; s < 15; ++s) {
            int idx = tid + (s << 9);
            if (idx < PP*43) {
                int row = rows_[s], qj = qjs_[s];
                int sr = (row == k) ? p : ((row == p) ? k : row);
                Qq[s]   = A4[sr*43 + qj];
                dums[s] = A[sr*AS + k];
                Pq[s]   = A4[p*43 + qj];
            }
        }
        __syncthreads();   // barrier 1: reads done

        // --- phase B: writes ---
        float invpv = 1.0f / pv;
        int kq = k >> 2, ke = k & 3;
#pragma unroll
        for (int s = 0; s < 15; ++s) {
            int idx = tid + (s << 9);
            if (idx < PP*43) {
                int row = rows_[s], qj = qjs_[s];
                float4 Pv = Pq[s];
                float sx = Pv.x * invpv, sy = Pv.y * invpv, sz = Pv.z * invpv, sw = Pv.w * invpv;
                if (qj == kq) {
                    sx = (ke == 0) ? invpv : sx;
                    sy = (ke == 1) ? invpv : sy;
                    sz = (ke == 2) ? invpv : sz;
                    sw = (ke == 3) ? invpv : sw;
                }
                float4 o;
                if (row == k) {
                    o.x = sx; o.y = sy; o.z = sz; o.w = sw;
                } else {
                    float4 Qv = Qq[s];
                    float bx = Qv.x, by = Qv.y, bz = Qv.z, bw = Qv.w;
                    if (qj == kq) {
                        bx = (ke==0) ? 0.0f : bx;
                        by = (ke==1) ? 0.0f : by;
                        bz = (ke==2) ? 0.0f : bz;
                        bw = (ke==3) ? 0.0f : bw;
                    }
                    float d = dums[s];
                    o.x = bx - d*sx; o.y = by - d*sy; o.z = bz - d*sz; o.w = bw - d*sw;
                }
                A4[row*43 + qj] = o;
            }
        }
        if (tid == 0) perm[k] = p;
        __syncthreads();   // barrier 2: writes visible
    }

    // undo row pivots as column swaps (reverse order); each thread owns one row -> no barriers
    if (tid < PP) {
        for (int k = PP - 1; k >= 0; --k) {
            int p = perm[k];
            if (p != k) {
                float t1 = A[tid*AS + k];
                A[tid*AS + k] = A[tid*AS + p];
                A[tid*AS + p] = t1;
            }
        }
    }
    __syncthreads();

    // prep2 tail: Pinv -> frag layout (6 ksteps, plain K)
    for (int o = tid; o < 6*2*11*512; o += 512) {
        int li = o & 511;
        int rest = o >> 9;
        int mt = rest % 11;
        int kp = rest / 11;
        int plane = kp & 1, ks = kp >> 1;
        int lane = li >> 3, j = li & 7;
        int row = mt*16 + (lane & 15);
        int kk = ks*32 + 8*(lane>>4) + j;
        float val = (row < PP && kk < PP) ? A[row*AS + kk] : 0.0f;
        ushort h = f2bf(val);
        ushort out = plane ? f2bf(val - bf2f(h)) : h;
        prep2[o] = out;
    }
}

// ---------------- fused: GEMM1 -> threshold/count -> GEMM2 -> fold ----------------
// 512 threads = 8 waves; wave w owns tile row (ho0+w), 16 cols. MFMA 16x16x32 bf16,
// split hi/lo (3 products). t kept per-wave in LDS as packed (hi<<16|lo).
__global__ __launch_bounds__(512, 2) void fused_kernel(
    const float* __restrict__ xpad,
    const ushort* __restrict__ prep1,
    const ushort* __restrict__ prep2,
    const float* __restrict__ sigma_,
    float* __restrict__ wmap,
    float* __restrict__ num)
{
    extern __shared__ char smem[];
    float* xr = (float*)smem;                    // 20*28 = 560 floats
    float* fp = (float*)(smem + 560*4);          // 560 floats
    uint*  tb = (uint*)(smem + 1120*4);          // 8 waves * 192*17

    int tid = threadIdx.x;
    int w = tid >> 6, l = tid & 63, q = l >> 4, c = l & 15;
    int n = blockIdx.z, ho0 = blockIdx.y * 8, wo0 = blockIdx.x * 16;
    float lam = 6.0f * sigma_[0];

    const float* xp = xpad + n*HP*HP;
    for (int idx = tid; idx < 560; idx += 512) {
        int i = (idx*586) >> 14;                 // idx/28 exact for idx<560
        int j = idx - i*28;
        int gi = ho0 + i; gi = (gi > HP-1) ? HP-1 : gi;
        int gj = wo0 + j; gj = (gj > HP-1) ? HP-1 : gj;
        xr[idx] = xp[gi*HP + gj];
        fp[idx] = 0.0f;
    }
    uint* twp = tb + w*3264;                     // this wave's t buffer [192][17]
    for (int kz = l; kz < 16*17; kz += 64) twp[176*17 + kz] = 0u;   // zero pad rows 176..191
    __syncthreads();

    f32x4 acc[11];
#pragma unroll
    for (int mt = 0; mt < 11; ++mt) acc[mt] = (f32x4){0.f,0.f,0.f,0.f};

    const short8_t* p1v = reinterpret_cast<const short8_t*>(prep1);
    const short8_t* p2v = reinterpret_cast<const short8_t*>(prep2);

    // ---- GEMM1: t = Pm1 @ patches (K padded: kpad = di*16+dj, 7 ksteps) ----
    for (int ks = 0; ks < 7; ++ks) {
        int di = 2*ks + (q >> 1);
        int dj0 = 8*(q & 1);
        bool rowok = (di < 13);
        const float* src = xr + (w + (rowok ? di : 0))*28 + c + dj0;
        short8_t bh, bl;
#pragma unroll
        for (int j = 0; j < 8; ++j) {
            float v = (rowok && (dj0 + j) < 13) ? src[j] : 0.0f;
            ushort h = f2bf(v);
            bh[j] = (short)h;
            bl[j] = (short)f2bf(v - bf2f(h));
        }
        const short8_t* Ah = p1v + (ks*2+0)*11*64 + l;
        const short8_t* Al = p1v + (ks*2+1)*11*64 + l;
#pragma unroll
        for (int mt = 0; mt < 11; ++mt) {
            short8_t ah = Ah[mt*64];
            short8_t al = Al[mt*64];
            acc[mt] = __builtin_amdgcn_mfma_f32_16x16x32_bf16(ah, bh, acc[mt], 0, 0, 0);
            acc[mt] = __builtin_amdgcn_mfma_f32_16x16x32_bf16(al, bh, acc[mt], 0, 0, 0);
            acc[mt] = __builtin_amdgcn_mfma_f32_16x16x32_bf16(ah, bl, acc[mt], 0, 0, 0);
        }
    }

    // ---- threshold, pack t to LDS, count nonzeros (rows 1..168) ----
    int cnt = 0;
#pragma unroll
    for (int mt = 0; mt < 11; ++mt) {
#pragma unroll
        for (int e = 0; e < 4; ++e) {
            int r = mt*16 + 4*q + e;
            float t0 = acc[mt][e];
            float d = t0 / lam;
            bool keep = fabsf(d) > 1.0f;
            float tv = keep ? d*lam : 0.0f;
            cnt += (keep && r > 0) ? 1 : 0;
            ushort h = f2bf(tv);
            ushort lo = f2bf(tv - bf2f(h));
            twp[r*17 + c] = ((uint)h << 16) | (uint)lo;
        }
    }
    cnt += __shfl_xor(cnt, 16);
    cnt += __shfl_xor(cnt, 32);
    int ho = ho0 + w, wo = wo0 + c;
    float wgt = 1.0f / (1.0f + (float)cnt);
    bool valid = (ho < HO) && (wo < HO);
    if (!valid) wgt = 0.0f;
    if (q == 0 && valid) wmap[(n*HO + ho)*HO + wo] = wgt;

    // ---- GEMM2: rec = Pinv @ t (6 ksteps, plain K) ----
#pragma unroll
    for (int mt = 0; mt < 11; ++mt) acc[mt] = (f32x4){0.f,0.f,0.f,0.f};

    for (int ks = 0; ks < 6; ++ks) {
        short8_t bh, bl;
#pragma unroll
        for (int j = 0; j < 8; ++j) {
            uint u = twp[(ks*32 + 8*q + j)*17 + c];
            bh[j] = (short)(u >> 16);
            bl[j] = (short)(u & 0xffffu);
        }
        const short8_t* Ah = p2v + (ks*2+0)*11*64 + l;
        const short8_t* Al = p2v + (ks*2+1)*11*64 + l;
#pragma unroll
        for (int mt = 0; mt < 11; ++mt) {
            short8_t ah = Ah[mt*64];
            short8_t al = Al[mt*64];
            acc[mt] = __builtin_amdgcn_mfma_f32_16x16x32_bf16(ah, bh, acc[mt], 0, 0, 0);
            acc[mt] = __builtin_amdgcn_mfma_f32_16x16x32_bf16(al, bh, acc[mt], 0, 0, 0);
            acc[mt] = __builtin_amdgcn_mfma_f32_16x16x32_bf16(ah, bl, acc[mt], 0, 0, 0);
        }
    }

    // ---- scale by w, fold into LDS footprint ----
#pragma unroll
    for (int mt = 0; mt < 11; ++mt) {
#pragma unroll
        for (int e = 0; e < 4; ++e) {
            int r = mt*16 + 4*q + e;
            if (r < PP) {
                int di = (r*158) >> 11;          // r/13 exact for r<169
                int dj = r - di*13;
                atomicAdd(&fp[(w + di)*28 + c + dj], acc[mt][e] * wgt);
            }
        }
    }
    __syncthreads();

    // ---- commit footprint to num ----
    float* nump = num + n*HP*HP;
    for (int idx = tid; idx < 560; idx += 512) {
        int i = (idx*586) >> 14;
        int j = idx - i*28;
        int gi = ho0 + i, gj = wo0 + j;
        if (gi < HP && gj < HP) atomicAdd(&nump[gi*HP + gj], fp[idx]);
    }
}

// ---------------- final: out = (num / box13(w) + 1)/2 (verified round 1) ----------------
__global__ __launch_bounds__(256) void final_kernel(const float* __restrict__ num,
                                                    const float* __restrict__ wmap,
                                                    float* __restrict__ out)
{
    __shared__ float wr[28][28];
    int tid = threadIdx.x;
    int n = blockIdx.z;
    int y0 = blockIdx.y * 16, x0 = blockIdx.x * 16;
    const float* wp = wmap + n*HO*HO;
    for (int idx = tid; idx < 28*28; idx += 256) {
        int i = idx / 28, j = idx - (idx/28)*28;
        wr[i][j] = wp[(y0 + i)*HO + (x0 + j)];
    }
    __syncthreads();
    int py = tid >> 4, px = tid & 15;
    float dv = 0.0f;
#pragma unroll
    for (int a = 0; a < 13; ++a)
#pragma unroll
        for (int b = 0; b < 13; ++b)
            dv += wr[py + a][px + b];
    int y = y0 + py, x = x0 + px;
    float nv = num[(n*HP + (y + 12))*HP + (x + 12)];
    out[(n*HIMG + y)*HIMG + x] = (nv / dv + 1.0f) * 0.5f;
}

extern "C" void kernel_launch(void* const* d_in, const int* in_sizes, int n_in,
                              void* d_out, int out_size, void* d_ws, size_t ws_size,
                              hipStream_t stream) {
    const float* x      = (const float*)d_in[0];
    const float* sigma_ = (const float*)d_in[1];
    const float* Pm1    = (const float*)d_in[2];
    float* ws    = (float*)d_ws;
    float* xpad  = ws;                         // 313600 f
    float* wmap  = ws + 313600;                // 287296 f
    float* num   = ws + 600896;                // 313600 f
    ushort* prep1 = (ushort*)(ws + 914496);    // 78848 ushorts
    ushort* prep2 = (ushort*)(ws + 953920);    // 67584 ushorts
    float* out   = (float*)d_out;

    const int INV_LDS   = PP*AS*4 + PP*4;          // 116948
    const int FUSED_LDS = 1120*4 + 8*3264*4;       // 108928
    hipFuncSetAttribute((const void*)invert_kernel, hipFuncAttributeMaxDynamicSharedMemorySize, INV_LDS);
    hipFuncSetAttribute((const void*)fused_kernel,  hipFuncAttributeMaxDynamicSharedMemorySize, FUSED_LDS);

    hipMemsetAsync(num, 0, (size_t)NIMG*HP*HP*sizeof(float), stream);
    pad_kernel<<<(NIMG*HP*HP + 255)/256, 256, 0, stream>>>(x, xpad);
    prep1_kernel<<<(7*11*512 + 255)/256, 256, 0, stream>>>(Pm1, prep1);
    invert_kernel<<<1, 512, INV_LDS, stream>>>(Pm1, prep2);
    dim3 grid((HO + 15)/16, (HO + 7)/8, NIMG);     // 17 x 34 x 4
    fused_kernel<<<grid, 512, FUSED_LDS, stream>>>(xpad, prep1, prep2, sigma_, wmap, num);
    dim3 gridD(HIMG/16, HIMG/16, NIMG);
    final_kernel<<<gridD, 256, 0, stream>>>(num, wmap, out);
}

// Round 3
// 990.041 us; speedup vs baseline: 1.8059x; 1.0800x over previous
//
#include <hip/hip_runtime.h>
#include <math.h>

#define P    13
#define PP   169
#define NIMG 4
#define HIMG 256
#define HP   280            // 256 + 2*12
#define HO   268            // 280 - 13 + 1

typedef __attribute__((ext_vector_type(8))) short short8_t;
typedef __attribute__((ext_vector_type(4))) float f32x4;

__device__ __forceinline__ ushort f2bf(float x) {
    union { float f; unsigned u; } a; a.f = x;
    unsigned r = a.u + 0x7fffu + ((a.u >> 16) & 1u);   // RNE
    return (ushort)(r >> 16);
}
__device__ __forceinline__ float bf2f(ushort b) {
    union { float f; unsigned u; } a; a.u = ((unsigned)b) << 16;
    return a.f;
}

// ---------------- pad (verified r1/r2) ----------------
__global__ void pad_kernel(const float* __restrict__ x, float* __restrict__ xpad) {
    int idx = blockIdx.x * blockDim.x + threadIdx.x;
    if (idx >= NIMG*HP*HP) return;
    int j = idx % HP; int t = idx / HP; int i = t % HP; int n = t / HP;
    int mi = i - (P-1); mi = (mi < 0) ? -mi : mi; mi = (mi >= HIMG) ? (2*(HIMG-1) - mi) : mi;
    int mj = j - (P-1); mj = (mj < 0) ? -mj : mj; mj = (mj >= HIMG) ? (2*(HIMG-1) - mj) : mj;
    xpad[idx] = 2.0f * x[(n*HIMG + mi)*HIMG + mj] - 1.0f;
}

// ---------------- prep1: Pm1 -> MFMA frag layout (PLAIN K), split bf16 hi/lo ----------------
// layout (ushort): ((ks*2+plane)*11 + mt)*512 + lane*8 + j
// value = Pm1[row][k], row = mt*16+(lane&15), k = ks*32+8*(lane>>4)+j ; zero outside
__global__ __launch_bounds__(256) void prep1_kernel(const float* __restrict__ Pm1,
                                                    ushort* __restrict__ prep1) {
    int idx = blockIdx.x*256 + threadIdx.x;
    if (idx >= 6*11*512) return;
    int j    = idx & 7;
    int lane = (idx >> 3) & 63;
    int rest = idx >> 9;
    int mt   = rest % 11;
    int ks   = rest / 11;
    int row  = mt*16 + (lane & 15);
    int k    = ks*32 + 8*(lane>>4) + j;
    float val = (row < PP && k < PP) ? Pm1[row*PP + k] : 0.0f;
    ushort h = f2bf(val);
    ushort lo = f2bf(val - bf2f(h));
    prep1[((ks*2+0)*11 + mt)*512 + lane*8 + j] = h;
    prep1[((ks*2+1)*11 + mt)*512 + lane*8 + j] = lo;
}

// ---------------- invert: register-blocked Gauss-Jordan w/ partial pivoting ----------------
// 512 threads = 32 row-groups (6 rows) x 16 col-groups (11 real cols, padded to 12).
// Per iter only pivot col + pivot row + swap row transit LDS. 2 barriers/iter.
__global__ __launch_bounds__(512) void invert_kernel(const float* __restrict__ Pm1,
                                                     ushort* __restrict__ prep2) {
    extern __shared__ float sm[];
    float* Adump = sm;                      // 169*192
    float* dcolB = sm + 169*192;            // 2*192
    float* prowB = dcolB + 384;             // 2*192
    float* krowB = prowB + 384;             // 2*192
    int*   perm  = (int*)(krowB + 384);     // 169

    int tid = threadIdx.x;
    int ti = tid >> 4, tj = tid & 15;
    int l64 = tid & 63;
    int row0 = 6*ti;

    float a[6][12];
#pragma unroll
    for (int m = 0; m < 6; ++m)
#pragma unroll
      for (int u = 0; u < 12; ++u) {
        int i = row0 + m, kc = 11*tj + u;
        a[m][u] = (i < PP && u < 11 && kc < PP) ? Pm1[i*PP + kc] : 0.0f;
      }
    __syncthreads();

    for (int k = 0; k < PP; ++k) {
        int par = k & 1;
        float* dcol = dcolB + par*192;
        float* prow = prowB + par*192;
        float* krow = krowB + par*192;
        int gk = (k*5958) >> 16;           // k/11
        int uk = k - 11*gk;
        // W1: col-k owners write current column k
        if (tj == gk) {
#pragma unroll
            for (int m = 0; m < 6; ++m) {
                float v = 0.0f;
#pragma unroll
                for (int u = 0; u < 12; ++u) v = (u == uk) ? a[m][u] : v;
                dcol[row0 + m] = v;
            }
        }
        __syncthreads();   // barrier A
        // pivot search (redundant per wave; deterministic packed key)
        unsigned key = 0;
        for (int i = k + l64; i < PP; i += 64) {
            unsigned bits = __float_as_uint(fabsf(dcol[i]));
            unsigned kk2 = (bits & 0xFFFFFF00u) | (unsigned)(255 - i);
            key = (kk2 > key) ? kk2 : key;
        }
#pragma unroll
        for (int m2 = 1; m2 < 64; m2 <<= 1) {
            unsigned ok = __shfl_xor(key, m2);
            key = (ok > key) ? ok : key;
        }
        int p = 255 - (int)(key & 0xFFu);
        float pv = dcol[p];
        int tip = (p*10923) >> 16;  int mp = p - 6*tip;   // p/6
        int tik = (k*10923) >> 16;  int mk = k - 6*tik;   // k/6
        if (ti == tip) {
#pragma unroll
            for (int m = 0; m < 6; ++m)
#pragma unroll
              for (int u = 0; u < 12; ++u)
                if (m == mp) prow[12*tj + u] = a[m][u];
        }
        if (ti == tik) {
#pragma unroll
            for (int m = 0; m < 6; ++m)
#pragma unroll
              for (int u = 0; u < 12; ++u)
                if (m == mk) krow[12*tj + u] = a[m][u];
        }
        if (tid == 0) perm[k] = p;
        __syncthreads();   // barrier B
        // update
        float invpv = 1.0f / pv;
        bool myg = (tj == gk);
        float s[12];
#pragma unroll
        for (int u = 0; u < 12; ++u) {
            float su = prow[12*tj + u] * invpv;
            s[u] = (myg && u == uk) ? invpv : su;
        }
        float d[6];
#pragma unroll
        for (int m = 0; m < 6; ++m) d[m] = dcol[row0 + m];
        float dk = dcol[k];
        float kr[12];
        if (ti == tip) {
#pragma unroll
            for (int u = 0; u < 12; ++u) kr[u] = krow[12*tj + u];
        }
#pragma unroll
        for (int m = 0; m < 6; ++m) {
            int i = row0 + m;
            bool isK = (i == k), isP = (i == p);
            float dum = isP ? dk : d[m];
#pragma unroll
            for (int u = 0; u < 12; ++u) {
                float b = isP ? kr[u] : a[m][u];
                b = (myg && u == uk) ? 0.0f : b;
                float nv = b - dum * s[u];
                a[m][u] = isK ? s[u] : nv;
            }
        }
    }
    __syncthreads();
    // dump to LDS
#pragma unroll
    for (int m = 0; m < 6; ++m) {
        int i = row0 + m;
        if (i < PP) {
#pragma unroll
            for (int u4 = 0; u4 < 3; ++u4) {
                float4 v; v.x = a[m][4*u4]; v.y = a[m][4*u4+1]; v.z = a[m][4*u4+2]; v.w = a[m][4*u4+3];
                *reinterpret_cast<float4*>(&Adump[i*192 + 12*tj + 4*u4]) = v;
            }
        }
    }
    __syncthreads();
    // undo row pivots as column swaps (reverse)
    if (tid < PP) {
        for (int k = PP - 1; k >= 0; --k) {
            int p = perm[k];
            if (p != k) {
                int gk2 = (k*5958)>>16, gp2 = (p*5958)>>16;
                int c1 = gk2*12 + (k - 11*gk2);
                int c2 = gp2*12 + (p - 11*gp2);
                float t1 = Adump[tid*192 + c1];
                Adump[tid*192 + c1] = Adump[tid*192 + c2];
                Adump[tid*192 + c2] = t1;
            }
        }
    }
    __syncthreads();
    // prep2: Pinv -> frag layout (plain K), split hi/lo
    for (int o = tid; o < 6*2*11*512; o += 512) {
        int li = o & 511;
        int rest = o >> 9;
        int mt = rest % 11;
        int kp = rest / 11;
        int plane = kp & 1, ks = kp >> 1;
        int lane = li >> 3, j = li & 7;
        int row = mt*16 + (lane & 15);
        int kk = ks*32 + 8*(lane>>4) + j;
        float val = 0.0f;
        if (row < PP && kk < PP) {
            int g = (kk*5958) >> 16;
            val = Adump[row*192 + g*12 + (kk - 11*g)];
        }
        ushort h = f2bf(val);
        prep2[o] = plane ? f2bf(val - bf2f(h)) : h;
    }
}

// ---------------- fused: Bpatch-build -> GEMM1 -> threshold -> GEMM2 -> fold ----------------
// Block = 64 positions (4 ho x 16 wo), 512 threads = 4 M-groups x 2 N-groups.
// A fragments in registers; patches & t share one LDS buffer in MFMA-B frag layout
// (chunk dword addr = (ksf*64 + lane)*12 + 4h ; 48B lane stride -> conflict-free b128).
__device__ __forceinline__ f32x4 mfma3(short8_t ah, short8_t al, short8_t bh, short8_t bl, f32x4 acc) {
    acc = __builtin_amdgcn_mfma_f32_16x16x32_bf16(ah, bh, acc, 0, 0, 0);
    acc = __builtin_amdgcn_mfma_f32_16x16x32_bf16(al, bh, acc, 0, 0, 0);
    acc = __builtin_amdgcn_mfma_f32_16x16x32_bf16(ah, bl, acc, 0, 0, 0);
    return acc;
}

__global__ __launch_bounds__(512, 2) void fused_kernel(
    const float* __restrict__ xpad,
    const ushort* __restrict__ prep1,
    const ushort* __restrict__ prep2,
    const float* __restrict__ sigma_,
    float* __restrict__ wmap,
    float* __restrict__ num)
{
    extern __shared__ char smem[];
    uint*  tb  = (uint*)smem;                       // 24*64*12 dwords = 73728 B
    float* fp  = (float*)(smem + 73728);            // 448 floats
    int*   cnt = (int*)(smem + 73728 + 1792);       // 64 ints

    int tid = threadIdx.x;
    int w = tid >> 6, l = tid & 63;
    int q = l >> 4, c = l & 15;
    int mg = w >> 1, ng = w & 1;
    int ntiles = (mg == 3) ? 2 : 3;
    int n = blockIdx.z, ho0 = blockIdx.y * 4, wo0 = blockIdx.x * 16;
    float lam = 6.0f * sigma_[0];
    const float* xp = xpad + n*HP*HP;

    for (int idx = tid; idx < 448; idx += 512) fp[idx] = 0.0f;
    if (tid < 64) cnt[tid] = 0;

    // ---- build Bpatch into tb (3 frags per wave) ----
#pragma unroll
    for (int b = 0; b < 3; ++b) {
        int ksf = w*3 + b;
        int ks = ksf >> 2, cfp = ksf & 3;
        uint pk[8];
#pragma unroll
        for (int j = 0; j < 8; ++j) {
            int k = ks*32 + 8*q + j;
            float v = 0.0f;
            if (k < PP) {
                int di = (k*5042) >> 16;          // k/13
                int dj = k - 13*di;
                int gi = ho0 + cfp + di;          // <= 279 always
                int gj = wo0 + c + dj; gj = (gj > HP-1) ? (HP-1) : gj;
                v = xp[gi*HP + gj];
            }
            ushort h = f2bf(v);
            pk[j] = ((uint)h << 16) | (uint)f2bf(v - bf2f(h));
        }
        uint* dst = tb + (ksf*64 + l)*12;
        uint4 v0; v0.x = pk[0]; v0.y = pk[1]; v0.z = pk[2]; v0.w = pk[3];
        uint4 v1; v1.x = pk[4]; v1.y = pk[5]; v1.z = pk[6]; v1.w = pk[7];
        *reinterpret_cast<uint4*>(dst)     = v0;
        *reinterpret_cast<uint4*>(dst + 4) = v1;
    }
    __syncthreads();   // b1: Bpatch ready

    const short8_t* p1v = reinterpret_cast<const short8_t*>(prep1);
    const short8_t* p2v = reinterpret_cast<const short8_t*>(prep2);

    short8_t A[3][6][2];
#pragma unroll
    for (int tt = 0; tt < 3; ++tt) if (tt < ntiles) {
        int mt = mg + 4*tt;
#pragma unroll
        for (int ks = 0; ks < 6; ++ks) {
            A[tt][ks][0] = p1v[((ks*2+0)*11 + mt)*64 + l];
            A[tt][ks][1] = p1v[((ks*2+1)*11 + mt)*64 + l];
        }
    }

    f32x4 acc[3][2];
#pragma unroll
    for (int tt = 0; tt < 3; ++tt)
#pragma unroll
      for (int cf = 0; cf < 2; ++cf) acc[tt][cf] = (f32x4){0.f,0.f,0.f,0.f};

    // ---- GEMM1 ----
#pragma unroll
    for (int ks = 0; ks < 6; ++ks) {
#pragma unroll
        for (int cf = 0; cf < 2; ++cf) {
            int ksf = ks*4 + 2*ng + cf;
            const uint* src = tb + (ksf*64 + l)*12;
            uint4 a0 = *reinterpret_cast<const uint4*>(src);
            uint4 a1 = *reinterpret_cast<const uint4*>(src + 4);
            union { short8_t s; uint d[4]; } H, L;
            H.d[0] = (a0.x >> 16) | (a0.y & 0xFFFF0000u);
            H.d[1] = (a0.z >> 16) | (a0.w & 0xFFFF0000u);
            H.d[2] = (a1.x >> 16) | (a1.y & 0xFFFF0000u);
            H.d[3] = (a1.z >> 16) | (a1.w & 0xFFFF0000u);
            L.d[0] = (a0.x & 0xFFFFu) | (a0.y << 16);
            L.d[1] = (a0.z & 0xFFFFu) | (a0.w << 16);
            L.d[2] = (a1.x & 0xFFFFu) | (a1.y << 16);
            L.d[3] = (a1.z & 0xFFFFu) | (a1.w << 16);
#pragma unroll
            for (int tt = 0; tt < 3; ++tt) if (tt < ntiles)
                acc[tt][cf] = mfma3(A[tt][ks][0], A[tt][ks][1], H.s, L.s, acc[tt][cf]);
        }
    }
    __syncthreads();   // b2: Bpatch reads done; tb reusable for t

    // ---- threshold, pack t into tb, count ----
    int cadd[2] = {0, 0};
#pragma unroll
    for (int tt = 0; tt < 3; ++tt) if (tt < ntiles) {
        int mt = mg + 4*tt;
#pragma unroll
        for (int cf = 0; cf < 2; ++cf) {
            uint pk[4];
#pragma unroll
            for (int e = 0; e < 4; ++e) {
                int r = mt*16 + 4*q + e;
                float dd = acc[tt][cf][e] / lam;
                bool keep = fabsf(dd) > 1.0f;
                float tv = keep ? dd*lam : 0.0f;
                cadd[cf] += (keep && r > 0 && r < PP) ? 1 : 0;
                ushort h = f2bf(tv);
                pk[e] = ((uint)h << 16) | (uint)f2bf(tv - bf2f(h));
            }
            if (mt < 11) {
                int r0 = mt*16 + 4*q;
                int ks2 = r0 >> 5, qp = (r0 >> 3) & 3, hh = (r0 >> 2) & 1;
                int ksf = ks2*4 + 2*ng + cf;
                uint4 v; v.x = pk[0]; v.y = pk[1]; v.z = pk[2]; v.w = pk[3];
                *reinterpret_cast<uint4*>(tb + (ksf*64 + 16*qp + c)*12 + 4*hh) = v;
            }
        }
    }
#pragma unroll
    for (int cf = 0; cf < 2; ++cf) {
        int v = cadd[cf];
        v += __shfl_xor(v, 16);
        v += __shfl_xor(v, 32);
        if (q == 0) atomicAdd(&cnt[32*ng + 16*cf + c], v);
    }

    // A2 fragments (reuse A regs)
#pragma unroll
    for (int tt = 0; tt < 3; ++tt) if (tt < ntiles) {
        int mt = mg + 4*tt;
#pragma unroll
        for (int ks = 0; ks < 6; ++ks) {
            A[tt][ks][0] = p2v[((ks*2+0)*11 + mt)*64 + l];
            A[tt][ks][1] = p2v[((ks*2+1)*11 + mt)*64 + l];
        }
    }
    __syncthreads();   // b3: t + cnt final

    float wgt[2];
#pragma unroll
    for (int cf = 0; cf < 2; ++cf) {
        int col = 32*ng + 16*cf + c;
        int cv = cnt[col];
        wgt[cf] = (wo0 + c < HO) ? 1.0f/(1.0f + (float)cv) : 0.0f;
        if (mg == 0 && q == 0 && wo0 + c < HO)
            wmap[(n*HO + ho0 + 2*ng + cf)*HO + wo0 + c] = wgt[cf];
    }

#pragma unroll
    for (int tt = 0; tt < 3; ++tt)
#pragma unroll
      for (int cf = 0; cf < 2; ++cf) acc[tt][cf] = (f32x4){0.f,0.f,0.f,0.f};

    // ---- GEMM2 ----
#pragma unroll
    for (int ks = 0; ks < 6; ++ks) {
#pragma unroll
        for (int cf = 0; cf < 2; ++cf) {
            int ksf = ks*4 + 2*ng + cf;
            const uint* src = tb + (ksf*64 + l)*12;
            uint4 a0 = *reinterpret_cast<const uint4*>(src);
            uint4 a1 = *reinterpret_cast<const uint4*>(src + 4);
            union { short8_t s; uint d[4]; } H, L;
            H.d[0] = (a0.x >> 16) | (a0.y & 0xFFFF0000u);
            H.d[1] = (a0.z >> 16) | (a0.w & 0xFFFF0000u);
            H.d[2] = (a1.x >> 16) | (a1.y & 0xFFFF0000u);
            H.d[3] = (a1.z >> 16) | (a1.w & 0xFFFF0000u);
            L.d[0] = (a0.x & 0xFFFFu) | (a0.y << 16);
            L.d[1] = (a0.z & 0xFFFFu) | (a0.w << 16);
            L.d[2] = (a1.x & 0xFFFFu) | (a1.y << 16);
            L.d[3] = (a1.z & 0xFFFFu) | (a1.w << 16);
#pragma unroll
            for (int tt = 0; tt < 3; ++tt) if (tt < ntiles)
                acc[tt][cf] = mfma3(A[tt][ks][0], A[tt][ks][1], H.s, L.s, acc[tt][cf]);
        }
    }

    // ---- scale by w, fold into footprint ----
#pragma unroll
    for (int tt = 0; tt < 3; ++tt) if (tt < ntiles) {
        int mt = mg + 4*tt;
#pragma unroll
        for (int cf = 0; cf < 2; ++cf) {
#pragma unroll
            for (int e = 0; e < 4; ++e) {
                int r = mt*16 + 4*q + e;
                if (r < PP) {
                    int di = (r*5042) >> 16;      // r/13
                    int dj = r - 13*di;
                    atomicAdd(&fp[(2*ng + cf + di)*28 + c + dj], acc[tt][cf][e] * wgt[cf]);
                }
            }
        }
    }
    __syncthreads();   // b4

    float* nump = num + n*HP*HP;
    for (int idx = tid; idx < 448; idx += 512) {
        int i = (idx*586) >> 14;                  // idx/28
        int j = idx - i*28;
        int gj = wo0 + j;
        if (gj < HP) atomicAdd(&nump[(ho0 + i)*HP + gj], fp[idx]);
    }
}

// ---------------- final: out = (num / box13(w) + 1)/2 (verified) ----------------
__global__ __launch_bounds__(256) void final_kernel(const float* __restrict__ num,
                                                    const float* __restrict__ wmap,
                                                    float* __restrict__ out)
{
    __shared__ float wr[28][28];
    int tid = threadIdx.x;
    int n = blockIdx.z;
    int y0 = blockIdx.y * 16, x0 = blockIdx.x * 16;
    const float* wp = wmap + n*HO*HO;
    for (int idx = tid; idx < 28*28; idx += 256) {
        int i = idx / 28, j = idx - (idx/28)*28;
        wr[i][j] = wp[(y0 + i)*HO + (x0 + j)];
    }
    __syncthreads();
    int py = tid >> 4, px = tid & 15;
    float dv = 0.0f;
#pragma unroll
    for (int a = 0; a < 13; ++a)
#pragma unroll
        for (int b = 0; b < 13; ++b)
            dv += wr[py + a][px + b];
    int y = y0 + py, x = x0 + px;
    float nv = num[(n*HP + (y + 12))*HP + (x + 12)];
    out[(n*HIMG + y)*HIMG + x] = (nv / dv + 1.0f) * 0.5f;
}

extern "C" void kernel_launch(void* const* d_in, const int* in_sizes, int n_in,
                              void* d_out, int out_size, void* d_ws, size_t ws_size,
                              hipStream_t stream) {
    const float* x      = (const float*)d_in[0];
    const float* sigma_ = (const float*)d_in[1];
    const float* Pm1    = (const float*)d_in[2];
    float* ws    = (float*)d_ws;
    float* xpad  = ws;                           // 313600 f
    float* wmap  = ws + 313600;                  // 287296 f
    float* num   = ws + 600896;                  // 313600 f
    ushort* prep1 = (ushort*)(ws + 914496);      // 67584 ushorts
    ushort* prep2 = (ushort*)(ws + 948288);      // 67584 ushorts
    float* out   = (float*)d_out;

    const int INV_LDS   = (169*192 + 3*384)*4 + 169*4;          // 135076
    const int FUSED_LDS = 73728 + 1792 + 256;                   // 75776
    hipFuncSetAttribute((const void*)invert_kernel, hipFuncAttributeMaxDynamicSharedMemorySize, INV_LDS);
    hipFuncSetAttribute((const void*)fused_kernel,  hipFuncAttributeMaxDynamicSharedMemorySize, FUSED_LDS);

    hipMemsetAsync(num, 0, (size_t)NIMG*HP*HP*sizeof(float), stream);
    pad_kernel<<<(NIMG*HP*HP + 255)/256, 256, 0, stream>>>(x, xpad);
    prep1_kernel<<<(6*11*512 + 255)/256, 256, 0, stream>>>(Pm1, prep1);
    invert_kernel<<<1, 512, INV_LDS, stream>>>(Pm1, prep2);
    dim3 grid((HO + 15)/16, (HO + 3)/4, NIMG);   // 17 x 67 x 4
    fused_kernel<<<grid, 512, FUSED_LDS, stream>>>(xpad, prep1, prep2, sigma_, wmap, num);
    dim3 gridD(HIMG/16, HIMG/16, NIMG);
    final_kernel<<<gridD, 256, 0, stream>>>(num, wmap, out);
}

// Round 4
// 766.109 us; speedup vs baseline: 2.3338x; 1.2923x over previous
//
#include <hip/hip_runtime.h>
#include <math.h>

#define P    13
#define PP   169
#define NIMG 4
#define HIMG 256
#define HP   280            // 256 + 2*12
#define HO   268            // 280 - 13 + 1

typedef __attribute__((ext_vector_type(8))) short short8_t;
typedef __attribute__((ext_vector_type(4))) float f32x4;

__device__ __forceinline__ ushort f2bf(float x) {
    union { float f; unsigned u; } a; a.f = x;
    unsigned r = a.u + 0x7fffu + ((a.u >> 16) & 1u);   // RNE
    return (ushort)(r >> 16);
}
__device__ __forceinline__ float bf2f(ushort b) {
    union { float f; unsigned u; } a; a.u = ((unsigned)b) << 16;
    return a.f;
}

// ---------------- prep1: Pm1 -> MFMA frag layout (plain K), split bf16 hi/lo ----------------
// layout (ushort): ((ks*2+plane)*11 + mt)*512 + lane*8 + j
__global__ __launch_bounds__(256) void prep1_kernel(const float* __restrict__ Pm1,
                                                    ushort* __restrict__ prep1) {
    int idx = blockIdx.x*256 + threadIdx.x;
    if (idx >= 6*11*512) return;
    int j    = idx & 7;
    int lane = (idx >> 3) & 63;
    int rest = idx >> 9;
    int mt   = rest % 11;
    int ks   = rest / 11;
    int row  = mt*16 + (lane & 15);
    int k    = ks*32 + 8*(lane>>4) + j;
    float val = (row < PP && k < PP) ? Pm1[row*PP + k] : 0.0f;
    ushort h = f2bf(val);
    ushort lo = f2bf(val - bf2f(h));
    prep1[((ks*2+0)*11 + mt)*512 + lane*8 + j] = h;
    prep1[((ks*2+1)*11 + mt)*512 + lane*8 + j] = lo;
}

// ---------------- invert: register-blocked Gauss-Jordan, scalar-branch fixups ----------------
// 512 threads = 32 row-groups (6 rows) x 16 col-groups (12 cols, 11 real).
__global__ __launch_bounds__(512, 2) void invert_kernel(const float* __restrict__ Pm1,
                                                        ushort* __restrict__ prep2) {
    extern __shared__ float sm[];
    float* Adump = sm;                      // 169*192
    float* dcolB = sm + 169*192;            // 2*192
    float* prowB = dcolB + 384;             // 2*192
    float* krowB = prowB + 384;             // 2*192
    int*   perm  = (int*)(krowB + 384);     // 169

    int tid = threadIdx.x;
    int ti = tid >> 4, tj = tid & 15;
    int l64 = tid & 63;
    int row0 = 6*ti;

    float a[6][12];
#pragma unroll
    for (int m = 0; m < 6; ++m)
#pragma unroll
      for (int u = 0; u < 12; ++u) {
        int i = row0 + m, kc = 11*tj + u;
        a[m][u] = (i < PP && u < 11 && kc < PP) ? Pm1[i*PP + kc] : 0.0f;
      }
    __syncthreads();

    for (int k = 0; k < PP; ++k) {
        int par = k & 1;
        float* dcol = dcolB + par*192;
        float* prow = prowB + par*192;
        float* krow = krowB + par*192;
        int gk = (k*5958) >> 16;           // k/11
        int uk = k - 11*gk;
        // publish current column k (owners; scalar branch on u==uk)
        if (tj == gk) {
#pragma unroll
            for (int u = 0; u < 12; ++u) if (u == uk) {
#pragma unroll
                for (int m = 0; m < 6; ++m) dcol[row0 + m] = a[m][u];
            }
        }
        __syncthreads();   // barrier A: dcol visible
        // pivot search (redundant per wave), carry signed value with the key
        unsigned key = 0; float val = 0.0f;
        for (int i = k + l64; i < PP; i += 64) {
            float v = dcol[i];
            unsigned bits = __float_as_uint(fabsf(v));
            unsigned kk2 = (bits & 0xFFFFFF00u) | (unsigned)(255 - i);
            if (kk2 > key) { key = kk2; val = v; }
        }
#pragma unroll
        for (int m2 = 1; m2 < 64; m2 <<= 1) {
            unsigned ok = __shfl_xor(key, m2);
            float    ov = __shfl_xor(val, m2);
            if (ok > key) { key = ok; val = ov; }
        }
        int p = 255 - (int)(key & 0xFFu);
        float pv = val;
        int tip = (p*10923) >> 16;  int mp = p - 6*tip;   // p/6
        int tik = (k*10923) >> 16;  int mk = k - 6*tik;   // k/6
        // publish pivot row p and row k (owners; scalar branch on m)
        if (ti == tip) {
#pragma unroll
            for (int m = 0; m < 6; ++m) if (m == mp) {
#pragma unroll
                for (int u4 = 0; u4 < 3; ++u4) {
                    float4 v4; v4.x=a[m][4*u4]; v4.y=a[m][4*u4+1]; v4.z=a[m][4*u4+2]; v4.w=a[m][4*u4+3];
                    *reinterpret_cast<float4*>(&prow[12*tj + 4*u4]) = v4;
                }
            }
        }
        if (ti == tik) {
#pragma unroll
            for (int m = 0; m < 6; ++m) if (m == mk) {
#pragma unroll
                for (int u4 = 0; u4 < 3; ++u4) {
                    float4 v4; v4.x=a[m][4*u4]; v4.y=a[m][4*u4+1]; v4.z=a[m][4*u4+2]; v4.w=a[m][4*u4+3];
                    *reinterpret_cast<float4*>(&krow[12*tj + 4*u4]) = v4;
                }
            }
        }
        if (tid == 0) perm[k] = p;
        __syncthreads();   // barrier B: prow/krow visible
        // ---- update ----
        float invpv = 1.0f / pv;
        float s[12];
        {
            float4 p0 = *reinterpret_cast<float4*>(&prow[12*tj]);
            float4 p1 = *reinterpret_cast<float4*>(&prow[12*tj + 4]);
            float4 p2 = *reinterpret_cast<float4*>(&prow[12*tj + 8]);
            s[0]=p0.x*invpv; s[1]=p0.y*invpv; s[2]=p0.z*invpv; s[3]=p0.w*invpv;
            s[4]=p1.x*invpv; s[5]=p1.y*invpv; s[6]=p1.z*invpv; s[7]=p1.w*invpv;
            s[8]=p2.x*invpv; s[9]=p2.y*invpv; s[10]=p2.z*invpv; s[11]=p2.w*invpv;
        }
        bool myg = (tj == gk);
        if (myg) {
#pragma unroll
            for (int u = 0; u < 12; ++u) if (u == uk) {
                s[u] = invpv;
#pragma unroll
                for (int m = 0; m < 6; ++m) a[m][u] = 0.0f;   // pre-zero col k
            }
        }
        float d[6];
#pragma unroll
        for (int m = 0; m < 6; ++m) d[m] = dcol[row0 + m];
        // common rank-1 update (rows k,p get garbage; overwritten below)
#pragma unroll
        for (int m = 0; m < 6; ++m)
#pragma unroll
          for (int u = 0; u < 12; ++u)
            a[m][u] = __builtin_fmaf(-d[m], s[u], a[m][u]);
        // row k overwrite: scaled pivot row
        if (ti == tik) {
#pragma unroll
            for (int m = 0; m < 6; ++m) if (m == mk) {
#pragma unroll
                for (int u = 0; u < 12; ++u) a[m][u] = s[u];
            }
        }
        // row p overwrite: old row k eliminated
        if (p != k && ti == tip) {
            float dk = dcol[k];
            float kr[12];
            float4 k0 = *reinterpret_cast<float4*>(&krow[12*tj]);
            float4 k1 = *reinterpret_cast<float4*>(&krow[12*tj + 4]);
            float4 k2 = *reinterpret_cast<float4*>(&krow[12*tj + 8]);
            kr[0]=k0.x; kr[1]=k0.y; kr[2]=k0.z; kr[3]=k0.w;
            kr[4]=k1.x; kr[5]=k1.y; kr[6]=k1.z; kr[7]=k1.w;
            kr[8]=k2.x; kr[9]=k2.y; kr[10]=k2.z; kr[11]=k2.w;
            if (myg) {
#pragma unroll
                for (int u = 0; u < 12; ++u) if (u == uk) kr[u] = 0.0f;
            }
#pragma unroll
            for (int m = 0; m < 6; ++m) if (m == mp) {
#pragma unroll
                for (int u = 0; u < 12; ++u) a[m][u] = __builtin_fmaf(-dk, s[u], kr[u]);
            }
        }
    }
    __syncthreads();
    // dump to LDS
#pragma unroll
    for (int m = 0; m < 6; ++m) {
        int i = row0 + m;
        if (i < PP) {
#pragma unroll
            for (int u4 = 0; u4 < 3; ++u4) {
                float4 v; v.x = a[m][4*u4]; v.y = a[m][4*u4+1]; v.z = a[m][4*u4+2]; v.w = a[m][4*u4+3];
                *reinterpret_cast<float4*>(&Adump[i*192 + 12*tj + 4*u4]) = v;
            }
        }
    }
    __syncthreads();
    // undo row pivots as column swaps (reverse)
    if (tid < PP) {
        for (int k = PP - 1; k >= 0; --k) {
            int p = perm[k];
            if (p != k) {
                int gk2 = (k*5958)>>16, gp2 = (p*5958)>>16;
                int c1 = gk2*12 + (k - 11*gk2);
                int c2 = gp2*12 + (p - 11*gp2);
                float t1 = Adump[tid*192 + c1];
                Adump[tid*192 + c1] = Adump[tid*192 + c2];
                Adump[tid*192 + c2] = t1;
            }
        }
    }
    __syncthreads();
    // prep2: Pinv -> frag layout (plain K), split hi/lo
    for (int o = tid; o < 6*2*11*512; o += 512) {
        int li = o & 511;
        int rest = o >> 9;
        int mt = rest % 11;
        int kp = rest / 11;
        int plane = kp & 1, ks = kp >> 1;
        int lane = li >> 3, j = li & 7;
        int row = mt*16 + (lane & 15);
        int kk = ks*32 + 8*(lane>>4) + j;
        float val = 0.0f;
        if (row < PP && kk < PP) {
            int g = (kk*5958) >> 16;
            val = Adump[row*192 + g*12 + (kk - 11*g)];
        }
        ushort h = f2bf(val);
        prep2[o] = plane ? f2bf(val - bf2f(h)) : h;
    }
}

// ---------------- fused: reflect-pad + Bpatch -> GEMM1 -> threshold -> GEMM2 -> fold ----------------
__device__ __forceinline__ f32x4 mfma3(short8_t ah, short8_t al, short8_t bh, short8_t bl, f32x4 acc) {
    acc = __builtin_amdgcn_mfma_f32_16x16x32_bf16(ah, bh, acc, 0, 0, 0);
    acc = __builtin_amdgcn_mfma_f32_16x16x32_bf16(al, bh, acc, 0, 0, 0);
    acc = __builtin_amdgcn_mfma_f32_16x16x32_bf16(ah, bl, acc, 0, 0, 0);
    return acc;
}

#define UNPACK_HL(src) \
    uint4 a0 = *reinterpret_cast<const uint4*>(src); \
    uint4 a1 = *reinterpret_cast<const uint4*>((src) + 4); \
    union { short8_t s; uint d[4]; } H, L; \
    H.d[0] = (a0.x >> 16) | (a0.y & 0xFFFF0000u); \
    H.d[1] = (a0.z >> 16) | (a0.w & 0xFFFF0000u); \
    H.d[2] = (a1.x >> 16) | (a1.y & 0xFFFF0000u); \
    H.d[3] = (a1.z >> 16) | (a1.w & 0xFFFF0000u); \
    L.d[0] = (a0.x & 0xFFFFu) | (a0.y << 16); \
    L.d[1] = (a0.z & 0xFFFFu) | (a0.w << 16); \
    L.d[2] = (a1.x & 0xFFFFu) | (a1.y << 16); \
    L.d[3] = (a1.z & 0xFFFFu) | (a1.w << 16);

__global__ __launch_bounds__(512, 4) void fused_kernel(
    const float* __restrict__ x,
    const ushort* __restrict__ prep1,
    const ushort* __restrict__ prep2,
    const float* __restrict__ sigma_,
    float* __restrict__ wmap,
    float* __restrict__ num)
{
    extern __shared__ char smem[];
    uint*  tb  = (uint*)smem;                       // 24*64*12 dwords = 73728 B
    float* fp  = (float*)(smem + 73728);            // 448 floats
    int*   cnt = (int*)(smem + 73728 + 1792);       // 64 ints

    int tid = threadIdx.x;
    int w = tid >> 6, l = tid & 63;
    int q = l >> 4, c = l & 15;
    int mg = w >> 1, ng = w & 1;
    int ntiles = (mg == 3) ? 2 : 3;
    int n = blockIdx.z, ho0 = blockIdx.y * 4, wo0 = blockIdx.x * 16;
    float lam = 6.0f * sigma_[0];
    const float* xn = x + n*HIMG*HIMG;

    for (int idx = tid; idx < 448; idx += 512) fp[idx] = 0.0f;
    if (tid < 64) cnt[tid] = 0;

    // ---- build Bpatch into tb (reflect-pad fused; 3 frags per wave) ----
#pragma unroll
    for (int b = 0; b < 3; ++b) {
        int ksf = w*3 + b;
        int ks = ksf >> 2, cfp = ksf & 3;
        uint pk[8];
#pragma unroll
        for (int j = 0; j < 8; ++j) {
            int k = ks*32 + 8*q + j;
            float v = 0.0f;
            if (k < PP) {
                int di = (k*5042) >> 16;          // k/13
                int dj = k - 13*di;
                int gi = ho0 + cfp + di - 12;
                gi = (gi < 0) ? -gi : gi; gi = (gi > HIMG-1) ? (2*(HIMG-1) - gi) : gi;
                int gj = wo0 + c + dj - 12;
                gj = (gj < 0) ? -gj : gj; gj = (gj > HIMG-1) ? (2*(HIMG-1) - gj) : gj;
                v = 2.0f * xn[gi*HIMG + gj] - 1.0f;
            }
            ushort h = f2bf(v);
            pk[j] = ((uint)h << 16) | (uint)f2bf(v - bf2f(h));
        }
        uint* dst = tb + (ksf*64 + l)*12;
        uint4 v0; v0.x = pk[0]; v0.y = pk[1]; v0.z = pk[2]; v0.w = pk[3];
        uint4 v1; v1.x = pk[4]; v1.y = pk[5]; v1.z = pk[6]; v1.w = pk[7];
        *reinterpret_cast<uint4*>(dst)     = v0;
        *reinterpret_cast<uint4*>(dst + 4) = v1;
    }

    const short8_t* p1v = reinterpret_cast<const short8_t*>(prep1);
    const short8_t* p2v = reinterpret_cast<const short8_t*>(prep2);

    // preload GEMM1 ks=0 A-frags (overlaps barrier)
    short8_t ahc[3], alc[3];
#pragma unroll
    for (int tt = 0; tt < 3; ++tt) if (tt < ntiles) {
        int mt = mg + 4*tt;
        ahc[tt] = p1v[(0*11 + mt)*64 + l];
        alc[tt] = p1v[(1*11 + mt)*64 + l];
    }

    f32x4 acc[3][2];
#pragma unroll
    for (int tt = 0; tt < 3; ++tt)
#pragma unroll
      for (int cf = 0; cf < 2; ++cf) acc[tt][cf] = (f32x4){0.f,0.f,0.f,0.f};

    __syncthreads();   // b1: Bpatch ready

    // ---- GEMM1 (A streamed from L2 with 1-deep prefetch) ----
#pragma unroll 1
    for (int ks = 0; ks < 6; ++ks) {
        short8_t ahn[3], aln[3];
        if (ks < 5) {
#pragma unroll
            for (int tt = 0; tt < 3; ++tt) if (tt < ntiles) {
                int mt = mg + 4*tt;
                ahn[tt] = p1v[((2*(ks+1)+0)*11 + mt)*64 + l];
                aln[tt] = p1v[((2*(ks+1)+1)*11 + mt)*64 + l];
            }
        }
#pragma unroll
        for (int cf = 0; cf < 2; ++cf) {
            int ksf = ks*4 + 2*ng + cf;
            const uint* src = tb + (ksf*64 + l)*12;
            UNPACK_HL(src)
#pragma unroll
            for (int tt = 0; tt < 3; ++tt) if (tt < ntiles)
                acc[tt][cf] = mfma3(ahc[tt], alc[tt], H.s, L.s, acc[tt][cf]);
        }
        if (ks < 5) {
#pragma unroll
            for (int tt = 0; tt < 3; ++tt) if (tt < ntiles) { ahc[tt] = ahn[tt]; alc[tt] = aln[tt]; }
        }
    }
    __syncthreads();   // b2: Bpatch reads done; tb reusable for t

    // ---- threshold, pack t into tb, count ----
    int cadd[2] = {0, 0};
#pragma unroll
    for (int tt = 0; tt < 3; ++tt) if (tt < ntiles) {
        int mt = mg + 4*tt;
#pragma unroll
        for (int cf = 0; cf < 2; ++cf) {
            uint pk[4];
#pragma unroll
            for (int e = 0; e < 4; ++e) {
                int r = mt*16 + 4*q + e;
                float dd = acc[tt][cf][e] / lam;
                bool keep = fabsf(dd) > 1.0f;
                float tv = keep ? dd*lam : 0.0f;
                cadd[cf] += (keep && r > 0 && r < PP) ? 1 : 0;
                ushort h = f2bf(tv);
                pk[e] = ((uint)h << 16) | (uint)f2bf(tv - bf2f(h));
            }
            if (mt < 11) {
                int r0 = mt*16 + 4*q;
                int ks2 = r0 >> 5, qp = (r0 >> 3) & 3, hh = (r0 >> 2) & 1;
                int ksf = ks2*4 + 2*ng + cf;
                uint4 v; v.x = pk[0]; v.y = pk[1]; v.z = pk[2]; v.w = pk[3];
                *reinterpret_cast<uint4*>(tb + (ksf*64 + 16*qp + c)*12 + 4*hh) = v;
            }
        }
    }
#pragma unroll
    for (int cf = 0; cf < 2; ++cf) {
        int v = cadd[cf];
        v += __shfl_xor(v, 16);
        v += __shfl_xor(v, 32);
        if (q == 0) atomicAdd(&cnt[32*ng + 16*cf + c], v);
    }

    // preload GEMM2 ks=0 A-frags (overlaps barrier)
#pragma unroll
    for (int tt = 0; tt < 3; ++tt) if (tt < ntiles) {
        int mt = mg + 4*tt;
        ahc[tt] = p2v[(0*11 + mt)*64 + l];
        alc[tt] = p2v[(1*11 + mt)*64 + l];
    }
    __syncthreads();   // b3: t + cnt final

    float wgt[2];
#pragma unroll
    for (int cf = 0; cf < 2; ++cf) {
        int col = 32*ng + 16*cf + c;
        int cv = cnt[col];
        wgt[cf] = (wo0 + c < HO) ? 1.0f/(1.0f + (float)cv) : 0.0f;
        if (mg == 0 && q == 0 && wo0 + c < HO)
            wmap[(n*HO + ho0 + 2*ng + cf)*HO + wo0 + c] = wgt[cf];
    }

#pragma unroll
    for (int tt = 0; tt < 3; ++tt)
#pragma unroll
      for (int cf = 0; cf < 2; ++cf) acc[tt][cf] = (f32x4){0.f,0.f,0.f,0.f};

    // ---- GEMM2 (A streamed) ----
#pragma unroll 1
    for (int ks = 0; ks < 6; ++ks) {
        short8_t ahn[3], aln[3];
        if (ks < 5) {
#pragma unroll
            for (int tt = 0; tt < 3; ++tt) if (tt < ntiles) {
                int mt = mg + 4*tt;
                ahn[tt] = p2v[((2*(ks+1)+0)*11 + mt)*64 + l];
                aln[tt] = p2v[((2*(ks+1)+1)*11 + mt)*64 + l];
            }
        }
#pragma unroll
        for (int cf = 0; cf < 2; ++cf) {
            int ksf = ks*4 + 2*ng + cf;
            const uint* src = tb + (ksf*64 + l)*12;
            UNPACK_HL(src)
#pragma unroll
            for (int tt = 0; tt < 3; ++tt) if (tt < ntiles)
                acc[tt][cf] = mfma3(ahc[tt], alc[tt], H.s, L.s, acc[tt][cf]);
        }
        if (ks < 5) {
#pragma unroll
            for (int tt = 0; tt < 3; ++tt) if (tt < ntiles) { ahc[tt] = ahn[tt]; alc[tt] = aln[tt]; }
        }
    }

    // ---- scale by w, fold into footprint ----
#pragma unroll
    for (int tt = 0; tt < 3; ++tt) if (tt < ntiles) {
        int mt = mg + 4*tt;
#pragma unroll
        for (int cf = 0; cf < 2; ++cf) {
#pragma unroll
            for (int e = 0; e < 4; ++e) {
                int r = mt*16 + 4*q + e;
                if (r < PP) {
                    int di = (r*5042) >> 16;      // r/13
                    int dj = r - 13*di;
                    atomicAdd(&fp[(2*ng + cf + di)*28 + c + dj], acc[tt][cf][e] * wgt[cf]);
                }
            }
        }
    }
    __syncthreads();   // b4

    float* nump = num + n*HP*HP;
    for (int idx = tid; idx < 448; idx += 512) {
        int i = (idx*586) >> 14;                  // idx/28
        int j = idx - i*28;
        int gj = wo0 + j;
        if (gj < HP) atomicAdd(&nump[(ho0 + i)*HP + gj], fp[idx]);
    }
}

// ---------------- final: out = (num / box13(w) + 1)/2 (verified) ----------------
__global__ __launch_bounds__(256) void final_kernel(const float* __restrict__ num,
                                                    const float* __restrict__ wmap,
                                                    float* __restrict__ out)
{
    __shared__ float wr[28][28];
    int tid = threadIdx.x;
    int n = blockIdx.z;
    int y0 = blockIdx.y * 16, x0 = blockIdx.x * 16;
    const float* wp = wmap + n*HO*HO;
    for (int idx = tid; idx < 28*28; idx += 256) {
        int i = idx / 28, j = idx - (idx/28)*28;
        wr[i][j] = wp[(y0 + i)*HO + (x0 + j)];
    }
    __syncthreads();
    int py = tid >> 4, px = tid & 15;
    float dv = 0.0f;
#pragma unroll
    for (int a = 0; a < 13; ++a)
#pragma unroll
        for (int b = 0; b < 13; ++b)
            dv += wr[py + a][px + b];
    int y = y0 + py, x = x0 + px;
    float nv = num[(n*HP + (y + 12))*HP + (x + 12)];
    out[(n*HIMG + y)*HIMG + x] = (nv / dv + 1.0f) * 0.5f;
}

extern "C" void kernel_launch(void* const* d_in, const int* in_sizes, int n_in,
                              void* d_out, int out_size, void* d_ws, size_t ws_size,
                              hipStream_t stream) {
    const float* x      = (const float*)d_in[0];
    const float* sigma_ = (const float*)d_in[1];
    const float* Pm1    = (const float*)d_in[2];
    float* ws    = (float*)d_ws;
    float* wmap  = ws;                           // 287296 f
    float* num   = ws + 287296;                  // 313600 f
    ushort* prep1 = (ushort*)(ws + 600896);      // 67584 ushorts
    ushort* prep2 = (ushort*)(ws + 634688);      // 67584 ushorts
    float* out   = (float*)d_out;

    const int INV_LDS   = (169*192 + 3*384)*4 + 169*4;          // 135076
    const int FUSED_LDS = 73728 + 1792 + 256;                   // 75776
    hipFuncSetAttribute((const void*)invert_kernel, hipFuncAttributeMaxDynamicSharedMemorySize, INV_LDS);
    hipFuncSetAttribute((const void*)fused_kernel,  hipFuncAttributeMaxDynamicSharedMemorySize, FUSED_LDS);

    hipMemsetAsync(num, 0, (size_t)NIMG*HP*HP*sizeof(float), stream);
    prep1_kernel<<<(6*11*512 + 255)/256, 256, 0, stream>>>(Pm1, prep1);
    invert_kernel<<<1, 512, INV_LDS, stream>>>(Pm1, prep2);
    dim3 grid((HO + 15)/16, (HO + 3)/4, NIMG);   // 17 x 67 x 4
    fused_kernel<<<grid, 512, FUSED_LDS, stream>>>(x, prep1, prep2, sigma_, wmap, num);
    dim3 gridD(HIMG/16, HIMG/16, NIMG);
    final_kernel<<<gridD, 256, 0, stream>>>(num, wmap, out);
}